// Round 3
// baseline (675.968 us; speedup 1.0000x reference)
//
#include <hip/hip_runtime.h>
#include <hip/hip_bf16.h>

#define N_PTS 250000
#define N_VOX 60000
#define MID   256
#define NCLS  20
#define BN_EPS 1e-5f

typedef __attribute__((ext_vector_type(8))) short short8;
typedef __attribute__((ext_vector_type(4))) float f32x4;
typedef unsigned int u32;

__device__ __forceinline__ unsigned short f2bf_rne(float f) {
    u32 u = __builtin_bit_cast(u32, f);
    u += 0x7FFFu + ((u >> 16) & 1u);
    return (unsigned short)(u >> 16);
}
__device__ __forceinline__ u32 pack2_rnd(float lo, float hi) {
    u32 a = __builtin_bit_cast(u32, lo) + 0x8000u;
    u32 b = __builtin_bit_cast(u32, hi) + 0x8000u;
    return __builtin_amdgcn_perm(b, a, 0x07060302);   // hi16(b)<<16 | hi16(a)
}
__device__ __forceinline__ float bf2f(unsigned short h) {
    return __builtin_bit_cast(float, ((u32)h) << 16);
}
__device__ __forceinline__ float bfLo(u32 w) { return __builtin_bit_cast(float, w << 16); }
__device__ __forceinline__ float bfHi(u32 w) { return __builtin_bit_cast(float, w & 0xFFFF0000u); }

// ---------------------------------------------------------------------------
// prep: W1 fp32 [256][512] -> two bf16 B-fragment buffers (K=256 each):
//   W1ps = cols 0..255 (point half), W1vs = cols 256..511 (voxel half)
//   frag (kt 0..7, ni 0..15), lane: short8 = W1[ni*16+(lane&15)][base_k + kt*32+(lane>>4)*8..]
// ---------------------------------------------------------------------------
__global__ __launch_bounds__(256) void prep_w1_kernel(
    const float* __restrict__ W1, unsigned short* __restrict__ W1ps,
    unsigned short* __restrict__ W1vs)
{
    const int idx = blockIdx.x * 256 + threadIdx.x;   // 0..16383
    const int half = idx >> 13;
    const int f = idx & 8191;
    const int lane = f & 63;
    const int ni = (f >> 6) & 15;
    const int kt = f >> 10;                           // 0..7
    const int n = ni * 16 + (lane & 15);
    const int k = half * 256 + kt * 32 + (lane >> 4) * 8;
    const float* src = W1 + (size_t)n * 512 + k;
    unsigned short v[8];
    #pragma unroll
    for (int j = 0; j < 8; ++j) v[j] = f2bf_rne(src[j]);
    unsigned short* dst = (half ? W1vs : W1ps) + (size_t)f * 8;
    ((ushort4*)dst)[0] = make_ushort4(v[0], v[1], v[2], v[3]);
    ((ushort4*)dst)[1] = make_ushort4(v[4], v[5], v[6], v[7]);
}

// ---------------------------------------------------------------------------
// gemm_y: Y[60000][256] = vox @ W1v^T + b1   (bf16 out)
// Barrier-free K-loop: A-frags direct global->reg (fp32, coalesced), B from
// W1vs (L2). Epilogue bounces through LDS for coalesced row-major stores.
// Tile 128x256, 4 waves (wm x wn = 2x2), wave = 64m x 128n, acc[4][8].
// ---------------------------------------------------------------------------
__global__ __launch_bounds__(256, 2) void gemm_y_kernel(
    const float* __restrict__ vox, const unsigned short* __restrict__ W1vs,
    const float* __restrict__ b1, unsigned short* __restrict__ Ybuf)
{
    __shared__ unsigned short Ys[128 * 264];

    const int tid = threadIdx.x;
    const int lane = tid & 63;
    const int wv = tid >> 6;
    const int wm = wv & 1;
    const int wn = wv >> 1;
    const int l15 = lane & 15;
    const int l4  = lane >> 4;
    const int rowBase = blockIdx.x * 128;

    const float* aRow[4];
    #pragma unroll
    for (int mi = 0; mi < 4; ++mi) {
        int rg = rowBase + wm * 64 + mi * 16 + l15;
        if (rg > N_VOX - 1) rg = N_VOX - 1;
        aRow[mi] = vox + (size_t)rg * 256 + l4 * 8;
    }

    f32x4 acc[4][8];
    #pragma unroll
    for (int mi = 0; mi < 4; ++mi)
        #pragma unroll
        for (int j = 0; j < 8; ++j) acc[mi][j] = (f32x4){0.f, 0.f, 0.f, 0.f};

    f32x4 arC[4][2], arN[4][2];
    #pragma unroll
    for (int mi = 0; mi < 4; ++mi) {
        arC[mi][0] = *(const f32x4*)(aRow[mi]);
        arC[mi][1] = *(const f32x4*)(aRow[mi] + 4);
    }

    #pragma unroll
    for (int kt = 0; kt < 8; ++kt) {
        short8 bfr[8];
        #pragma unroll
        for (int j = 0; j < 8; ++j)
            bfr[j] = *(const short8*)(W1vs + ((size_t)(kt * 16 + wn * 8 + j) * 64 + lane) * 8);
        if (kt < 7) {
            #pragma unroll
            for (int mi = 0; mi < 4; ++mi) {
                arN[mi][0] = *(const f32x4*)(aRow[mi] + (kt + 1) * 32);
                arN[mi][1] = *(const f32x4*)(aRow[mi] + (kt + 1) * 32 + 4);
            }
        }
        short8 afr[4];
        #pragma unroll
        for (int mi = 0; mi < 4; ++mi) {
            u32* ap = (u32*)&afr[mi];
            ap[0] = pack2_rnd(arC[mi][0][0], arC[mi][0][1]);
            ap[1] = pack2_rnd(arC[mi][0][2], arC[mi][0][3]);
            ap[2] = pack2_rnd(arC[mi][1][0], arC[mi][1][1]);
            ap[3] = pack2_rnd(arC[mi][1][2], arC[mi][1][3]);
        }
        #pragma unroll
        for (int mi = 0; mi < 4; ++mi)
            #pragma unroll
            for (int j = 0; j < 8; ++j)
                acc[mi][j] = __builtin_amdgcn_mfma_f32_16x16x32_bf16(
                                 afr[mi], bfr[j], acc[mi][j], 0, 0, 0);
        #pragma unroll
        for (int mi = 0; mi < 4; ++mi) { arC[mi][0] = arN[mi][0]; arC[mi][1] = arN[mi][1]; }
    }

    // epilogue: +b1, bf16 into LDS, then coalesced stores
    #pragma unroll
    for (int j = 0; j < 8; ++j) {
        const int col = wn * 128 + j * 16 + l15;
        const float b1v = b1[col];
        #pragma unroll
        for (int mi = 0; mi < 4; ++mi)
            #pragma unroll
            for (int r = 0; r < 4; ++r) {
                const int lr = wm * 64 + mi * 16 + l4 * 4 + r;
                Ys[lr * 264 + col] = f2bf_rne(acc[mi][j][r] + b1v);
            }
    }
    __syncthreads();
    {
        const int lr = tid >> 1;
        const int rg = rowBase + lr;
        if (rg < N_VOX) {
            const unsigned short* src = &Ys[lr * 264 + (tid & 1) * 128];
            unsigned short* dst = Ybuf + (size_t)rg * 256 + (tid & 1) * 128;
            #pragma unroll
            for (int i = 0; i < 16; ++i)
                *(uint4*)(dst + i * 8) = *(const uint4*)(src + i * 8);
        }
    }
}

// ---------------------------------------------------------------------------
// gemm1: h[250000][256] = point @ W1p^T + Y[p2v]   (bf16 out + BN stats)
// Barrier-free K-loop (K=256): A direct global->reg, B from W1ps (L2).
// Epilogue: stage gathered Y rows into LDS, add, stats (LDS reduce -> one
// global atomic per column), coalesced h stores via LDS.
// ---------------------------------------------------------------------------
__global__ __launch_bounds__(256, 2) void gemm1_kernel(
    const float* __restrict__ point, const unsigned short* __restrict__ W1ps,
    const unsigned short* __restrict__ Ybuf, const int* __restrict__ p2v,
    unsigned short* __restrict__ hbuf,
    float* __restrict__ colsum, float* __restrict__ colsumsq)
{
    __shared__ unsigned short Ys[128 * 264];   // 66 KB, rows padded to 264 shorts
    __shared__ float scol[256], ssq[256];

    const int tid = threadIdx.x;
    scol[tid] = 0.f;
    ssq[tid] = 0.f;

    const int lane = tid & 63;
    const int wv = tid >> 6;
    const int wm = wv & 1;
    const int wn = wv >> 1;
    const int l15 = lane & 15;
    const int l4  = lane >> 4;
    const int rowBase = blockIdx.x * 128;

    const float* aRow[4];
    #pragma unroll
    for (int mi = 0; mi < 4; ++mi) {
        int rg = rowBase + wm * 64 + mi * 16 + l15;
        if (rg > N_PTS - 1) rg = N_PTS - 1;
        aRow[mi] = point + (size_t)rg * 256 + l4 * 8;
    }

    f32x4 acc[4][8];
    #pragma unroll
    for (int mi = 0; mi < 4; ++mi)
        #pragma unroll
        for (int j = 0; j < 8; ++j) acc[mi][j] = (f32x4){0.f, 0.f, 0.f, 0.f};

    f32x4 arC[4][2], arN[4][2];
    #pragma unroll
    for (int mi = 0; mi < 4; ++mi) {
        arC[mi][0] = *(const f32x4*)(aRow[mi]);
        arC[mi][1] = *(const f32x4*)(aRow[mi] + 4);
    }

    #pragma unroll
    for (int kt = 0; kt < 8; ++kt) {
        short8 bfr[8];
        #pragma unroll
        for (int j = 0; j < 8; ++j)
            bfr[j] = *(const short8*)(W1ps + ((size_t)(kt * 16 + wn * 8 + j) * 64 + lane) * 8);
        if (kt < 7) {
            #pragma unroll
            for (int mi = 0; mi < 4; ++mi) {
                arN[mi][0] = *(const f32x4*)(aRow[mi] + (kt + 1) * 32);
                arN[mi][1] = *(const f32x4*)(aRow[mi] + (kt + 1) * 32 + 4);
            }
        }
        short8 afr[4];
        #pragma unroll
        for (int mi = 0; mi < 4; ++mi) {
            u32* ap = (u32*)&afr[mi];
            ap[0] = pack2_rnd(arC[mi][0][0], arC[mi][0][1]);
            ap[1] = pack2_rnd(arC[mi][0][2], arC[mi][0][3]);
            ap[2] = pack2_rnd(arC[mi][1][0], arC[mi][1][1]);
            ap[3] = pack2_rnd(arC[mi][1][2], arC[mi][1][3]);
        }
        #pragma unroll
        for (int mi = 0; mi < 4; ++mi)
            #pragma unroll
            for (int j = 0; j < 8; ++j)
                acc[mi][j] = __builtin_amdgcn_mfma_f32_16x16x32_bf16(
                                 afr[mi], bfr[j], acc[mi][j], 0, 0, 0);
        #pragma unroll
        for (int mi = 0; mi < 4; ++mi) { arC[mi][0] = arN[mi][0]; arC[mi][1] = arN[mi][1]; }
    }

    // ---- stage gathered Y rows (bf16, 512 B each) into LDS ----
    {
        const int lr = tid >> 1;
        int rg = rowBase + lr;
        if (rg > N_PTS - 1) rg = N_PTS - 1;
        const unsigned short* ysrc = Ybuf + (size_t)p2v[rg] * 256 + (tid & 1) * 128;
        unsigned short* ydst = &Ys[lr * 264 + (tid & 1) * 128];
        #pragma unroll
        for (int i = 0; i < 16; ++i)
            *(uint4*)(ydst + i * 8) = *(const uint4*)(ysrc + i * 8);
    }
    __syncthreads();

    // ---- Y-add (in place in LDS) + per-column stats ----
    #pragma unroll
    for (int j = 0; j < 8; ++j) {
        const int col = wn * 128 + j * 16 + l15;
        float s = 0.f, sq = 0.f;
        #pragma unroll
        for (int mi = 0; mi < 4; ++mi) {
            #pragma unroll
            for (int r = 0; r < 4; ++r) {
                const int lr = wm * 64 + mi * 16 + l4 * 4 + r;
                unsigned short* p = &Ys[lr * 264 + col];
                const float hv = acc[mi][j][r] + bf2f(*p);
                *p = f2bf_rne(hv);
                if (rowBase + lr < N_PTS) { s += hv; sq += hv * hv; }
            }
        }
        s  += __shfl_xor(s, 16);  s  += __shfl_xor(s, 32);
        sq += __shfl_xor(sq, 16); sq += __shfl_xor(sq, 32);
        if (l4 == 0) {
            atomicAdd(&scol[col], s);
            atomicAdd(&ssq[col], sq);
        }
    }
    __syncthreads();

    // ---- coalesced h stores + one global atomic per column ----
    {
        const int lr = tid >> 1;
        const int rg = rowBase + lr;
        if (rg < N_PTS) {
            const unsigned short* src = &Ys[lr * 264 + (tid & 1) * 128];
            unsigned short* dst = hbuf + (size_t)rg * 256 + (tid & 1) * 128;
            #pragma unroll
            for (int i = 0; i < 16; ++i)
                *(uint4*)(dst + i * 8) = *(const uint4*)(src + i * 8);
        }
        atomicAdd(&colsum[tid], scol[tid]);
        atomicAdd(&colsumsq[tid], ssq[tid]);
    }
}

// ---------------------------------------------------------------------------
// cls_acc[c][f] = sum_b softmax(logits)[b][c] * vox[b][f]
// ---------------------------------------------------------------------------
#define NCHUNK 938
__global__ __launch_bounds__(256) void cls_acc_kernel(
    const float* __restrict__ logits, const float* __restrict__ vox,
    float* __restrict__ cls_acc)
{
    __shared__ float probs[64 * 24];
    const int tid = threadIdx.x;
    float acc[NCLS];
    #pragma unroll
    for (int c = 0; c < NCLS; ++c) acc[c] = 0.f;

    for (int ci = 0; ci < 4; ++ci) {
        const int chunk = blockIdx.x * 4 + ci;
        if (chunk >= NCHUNK) break;
        const int v0 = chunk * 64;
        __syncthreads();
        if (tid < 64) {
            const int v = v0 + tid;
            if (v < N_VOX) {
                float l[NCLS];
                float mx = -1e30f;
                #pragma unroll
                for (int c = 0; c < NCLS; ++c) {
                    l[c] = logits[(size_t)v * NCLS + c];
                    mx = fmaxf(mx, l[c]);
                }
                float sum = 0.f;
                #pragma unroll
                for (int c = 0; c < NCLS; ++c) { l[c] = __expf(l[c] - mx); sum += l[c]; }
                const float inv = 1.f / sum;
                #pragma unroll
                for (int c = 0; c < NCLS; ++c) probs[tid * 24 + c] = l[c] * inv;
            }
        }
        __syncthreads();
        const int nb = min(64, N_VOX - v0);
        for (int b = 0; b < nb; ++b) {
            const float vv = vox[(size_t)(v0 + b) * 256 + tid];
            #pragma unroll
            for (int c4 = 0; c4 < 5; ++c4) {
                const float4 p = *(const float4*)&probs[b * 24 + c4 * 4];
                acc[c4 * 4 + 0] += p.x * vv;
                acc[c4 * 4 + 1] += p.y * vv;
                acc[c4 * 4 + 2] += p.z * vv;
                acc[c4 * 4 + 3] += p.w * vv;
            }
        }
    }
    #pragma unroll
    for (int c = 0; c < NCLS; ++c)
        atomicAdd(&cls_acc[c * 256 + tid], acc[c]);
}

// ---------------------------------------------------------------------------
// fuse: BN1 stats -> scl/shf; cls_fin = BN20(cls_acc@W2^T+b2); bake B-frags
// for gemm2.
// ---------------------------------------------------------------------------
__global__ __launch_bounds__(256) void fuse_kernel(
    const float* __restrict__ colsum, const float* __restrict__ colsumsq,
    const float* __restrict__ g1, const float* __restrict__ be1,
    float* __restrict__ scl, float* __restrict__ shf,
    const float* __restrict__ cls_acc, const float* __restrict__ W2,
    const float* __restrict__ b2, const float* __restrict__ g2,
    const float* __restrict__ be2, unsigned short* __restrict__ cls_frag)
{
    __shared__ float cf[NCLS * 256];
    __shared__ float cf2[NCLS * 256];
    const int tid = threadIdx.x;

    {
        const float mean = colsum[tid] * (1.0f / N_PTS);
        const float var  = colsumsq[tid] * (1.0f / N_PTS) - mean * mean;
        const float sc = g1[tid] * rsqrtf(var + BN_EPS);
        scl[tid] = sc;
        shf[tid] = be1[tid] - mean * sc;
    }

    for (int i = tid; i < NCLS * 256; i += 256) cf[i] = cls_acc[i];
    __syncthreads();

    float acc[NCLS];
    #pragma unroll
    for (int c = 0; c < NCLS; ++c) acc[c] = b2[tid];
    for (int k = 0; k < 256; k += 4) {
        const float4 w = *(const float4*)&W2[(size_t)tid * 256 + k];
        #pragma unroll
        for (int c = 0; c < NCLS; ++c) {
            const float4 f = *(const float4*)&cf[c * 256 + k];
            acc[c] += w.x * f.x + w.y * f.y + w.z * f.z + w.w * f.w;
        }
    }
    float mean = 0.f;
    #pragma unroll
    for (int c = 0; c < NCLS; ++c) mean += acc[c];
    mean *= (1.f / NCLS);
    float var = 0.f;
    #pragma unroll
    for (int c = 0; c < NCLS; ++c) { const float d = acc[c] - mean; var += d * d; }
    var *= (1.f / NCLS);
    const float sc = g2[tid] * rsqrtf(var + BN_EPS);
    const float bb = be2[tid];
    #pragma unroll
    for (int c = 0; c < NCLS; ++c)
        cf2[c * 256 + tid] = (acc[c] - mean) * sc + bb;
    __syncthreads();

    #pragma unroll
    for (int i = 0; i < 4; ++i) {
        const int idx = i * 256 + tid;
        const int lane = idx & 63;
        const int ni = (idx >> 6) & 1;
        const int kt = idx >> 7;
        const int n = ni * 16 + (lane & 15);
        const int k = kt * 32 + (lane >> 4) * 8;
        unsigned short v[8];
        #pragma unroll
        for (int j = 0; j < 8; ++j)
            v[j] = (n < NCLS) ? f2bf_rne(cf2[n * 256 + k + j]) : (unsigned short)0;
        ushort4* dst = (ushort4*)(cls_frag + (size_t)idx * 8);
        dst[0] = make_ushort4(v[0], v[1], v[2], v[3]);
        dst[1] = make_ushort4(v[4], v[5], v[6], v[7]);
    }
}

// ---------------------------------------------------------------------------
// gemm2: out = relu(h*scl+shf) @ cls_fin^T  (bf16 MFMA, barrier-free K-loop)
// ---------------------------------------------------------------------------
__global__ __launch_bounds__(256) void gemm2_kernel(
    const unsigned short* __restrict__ hbuf,
    const float* __restrict__ scl, const float* __restrict__ shf,
    const unsigned short* __restrict__ cls_frag,
    float* __restrict__ out)
{
    __shared__ float sS[256], sT[256];
    const int tid = threadIdx.x;
    sS[tid] = scl[tid];
    sT[tid] = shf[tid];
    __syncthreads();

    const int lane = tid & 63;
    const int w = tid >> 6;
    const int l15 = lane & 15;
    const int l4 = lane >> 4;
    const int mBase = blockIdx.x * 256 + w * 64;

    f32x4 acc[4][2];
    #pragma unroll
    for (int mi = 0; mi < 4; ++mi) {
        acc[mi][0] = (f32x4){0.f, 0.f, 0.f, 0.f};
        acc[mi][1] = (f32x4){0.f, 0.f, 0.f, 0.f};
    }

    #pragma unroll
    for (int kt = 0; kt < 8; ++kt) {
        const int k0 = kt * 32 + l4 * 8;
        const short8 bf0 = *(const short8*)(cls_frag + ((kt * 2 + 0) * 64 + lane) * 8);
        const short8 bf1 = *(const short8*)(cls_frag + ((kt * 2 + 1) * 64 + lane) * 8);
        const f32x4 s0 = *(const f32x4*)&sS[k0];
        const f32x4 s1 = *(const f32x4*)&sS[k0 + 4];
        const f32x4 t0 = *(const f32x4*)&sT[k0];
        const f32x4 t1 = *(const f32x4*)&sT[k0 + 4];
        const float sv[8] = {s0[0], s0[1], s0[2], s0[3], s1[0], s1[1], s1[2], s1[3]};
        const float tv[8] = {t0[0], t0[1], t0[2], t0[3], t1[0], t1[1], t1[2], t1[3]};

        #pragma unroll
        for (int mi = 0; mi < 4; ++mi) {
            int m = mBase + mi * 16 + l15;
            if (m > N_PTS - 1) m = N_PTS - 1;
            const uint4 hx = *(const uint4*)(hbuf + (size_t)m * 256 + k0);
            const u32 wd[4] = {hx.x, hx.y, hx.z, hx.w};
            short8 a;
            u32* ap = (u32*)&a;
            #pragma unroll
            for (int p = 0; p < 4; ++p) {
                const float x0 = fmaxf(fmaf(bfLo(wd[p]), sv[2 * p],     tv[2 * p]),     0.f);
                const float x1 = fmaxf(fmaf(bfHi(wd[p]), sv[2 * p + 1], tv[2 * p + 1]), 0.f);
                ap[p] = pack2_rnd(x0, x1);
            }
            acc[mi][0] = __builtin_amdgcn_mfma_f32_16x16x32_bf16(a, bf0, acc[mi][0], 0, 0, 0);
            acc[mi][1] = __builtin_amdgcn_mfma_f32_16x16x32_bf16(a, bf1, acc[mi][1], 0, 0, 0);
        }
    }

    #pragma unroll
    for (int mi = 0; mi < 4; ++mi)
        #pragma unroll
        for (int ni = 0; ni < 2; ++ni) {
            const int n = ni * 16 + l15;
            #pragma unroll
            for (int r = 0; r < 4; ++r) {
                const int m = mBase + mi * 16 + l4 * 4 + r;
                if (n < NCLS && m < N_PTS)
                    out[(size_t)m * 20 + n] = acc[mi][ni][r];
            }
        }
}

// ---------------------------------------------------------------------------
extern "C" void kernel_launch(void* const* d_in, const int* in_sizes, int n_in,
                              void* d_out, int out_size, void* d_ws, size_t ws_size,
                              hipStream_t stream)
{
    const float* point  = (const float*)d_in[0];
    const float* vox    = (const float*)d_in[1];
    const float* logits = (const float*)d_in[2];
    const float* W1     = (const float*)d_in[3];
    const float* b1     = (const float*)d_in[4];
    const float* g1     = (const float*)d_in[5];
    const float* be1    = (const float*)d_in[6];
    const float* W2     = (const float*)d_in[7];
    const float* b2     = (const float*)d_in[8];
    const float* g2     = (const float*)d_in[9];
    const float* be2    = (const float*)d_in[10];
    const int*   p2v    = (const int*)d_in[11];
    float* out = (float*)d_out;

    char* ws = (char*)d_ws;
    unsigned short* hbuf = (unsigned short*)ws;
    size_t o = (size_t)N_PTS * 256 * 2;                               // 128 MB
    unsigned short* Ybuf = (unsigned short*)(ws + o); o += (size_t)N_VOX * 256 * 2;  // 30.7 MB
    float* colsum   = (float*)(ws + o); o += 1024;
    float* colsumsq = (float*)(ws + o); o += 1024;
    float* scl      = (float*)(ws + o); o += 1024;
    float* shf      = (float*)(ws + o); o += 1024;
    float* cls_acc  = (float*)(ws + o); o += (size_t)NCLS * 256 * 4;
    unsigned short* W1ps     = (unsigned short*)(ws + o); o += (size_t)8192 * 8 * 2;   // 128 KB
    unsigned short* W1vs     = (unsigned short*)(ws + o); o += (size_t)8192 * 8 * 2;   // 128 KB
    unsigned short* cls_frag = (unsigned short*)(ws + o); o += (size_t)1024 * 8 * 2;   // 16 KB

    hipMemsetAsync(colsum, 0, 2 * 1024, stream);
    hipMemsetAsync(cls_acc, 0, (size_t)NCLS * 256 * 4, stream);

    prep_w1_kernel<<<64, 256, 0, stream>>>(W1, W1ps, W1vs);
    gemm_y_kernel<<<469, 256, 0, stream>>>(vox, W1vs, b1, Ybuf);
    gemm1_kernel<<<1954, 256, 0, stream>>>(point, W1ps, Ybuf, p2v,
                                           hbuf, colsum, colsumsq);
    cls_acc_kernel<<<235, 256, 0, stream>>>(logits, vox, cls_acc);
    fuse_kernel<<<1, 256, 0, stream>>>(colsum, colsumsq, g1, be1, scl, shf,
                                       cls_acc, W2, b2, g2, be2, cls_frag);
    gemm2_kernel<<<977, 256, 0, stream>>>(hbuf, scl, shf, cls_frag, out);
}